// Round 1
// baseline (753.698 us; speedup 1.0000x reference)
//
#include <hip/hip_runtime.h>
#include <hip/hip_bf16.h>
#include <stdint.h>

#define NTILES 4
#define DMODEL 1024
#define DFF    4096
#define NTOK   16384

typedef __bf16 bf16x8 __attribute__((ext_vector_type(8)));
typedef float  f32x4  __attribute__((ext_vector_type(4)));

__device__ __forceinline__ uint16_t f2bf(float f) {
    union { float f; uint32_t u; } v; v.f = f;
    uint32_t u = v.u;
    uint32_t r = (u + 0x7fffu + ((u >> 16) & 1u)) >> 16;
    return (uint16_t)r;
}

#define GLOAD_LDS16(g, l) __builtin_amdgcn_global_load_lds( \
    (__attribute__((address_space(1))) void*)(g), \
    (__attribute__((address_space(3))) void*)(l), 16, 0, 0)

// ---------------- init: zero expert counts ----------------
__global__ void k_init(int* counts) {
    if (threadIdx.x < NTILES) counts[threadIdx.x] = 0;
}

// ---------------- signatures: partial column sums of Wup over f ----------------
// grid (8 fb, 16 cb, 4 e), 256 threads = 64 c x 4 f-subs
__global__ void k_sig_partial(const float* __restrict__ Wup, double* __restrict__ partial) {
    int e = blockIdx.z, cb = blockIdx.y, fb = blockIdx.x;
    int lc = threadIdx.x & 63;
    int fs = threadIdx.x >> 6;
    int c  = cb * 64 + lc;
    const float* base = Wup + (size_t)e * DFF * DMODEL + c;
    int f0 = fb * (DFF / 8);   // 512 rows per fb
    double s = 0.0;
    for (int i = 0; i < 128; ++i) {
        int f = f0 + i * 4 + fs;
        s += (double)base[(size_t)f * DMODEL];
    }
    __shared__ double red[4][64];
    red[fs][lc] = s;
    __syncthreads();
    if (fs == 0) {
        double t = red[0][lc] + red[1][lc] + red[2][lc] + red[3][lc];
        partial[((size_t)e * DMODEL + c) * 8 + fb] = t;
    }
}

__global__ void k_sig_final(const double* __restrict__ partial, float* __restrict__ sig) {
    int idx = blockIdx.x * 256 + threadIdx.x;   // 0..4095
    double s = 0.0;
    for (int fb = 0; fb < 8; ++fb) s += partial[(size_t)idx * 8 + fb];
    sig[idx] = (s > 0.0) ? 1.0f : ((s < 0.0) ? -1.0f : 0.0f);
}

// ---------------- routing: scores, argmax, gate, xb (bf16 copy), buckets ----------------
__global__ void __launch_bounds__(256) k_route(const float* __restrict__ x,
                                               const float* __restrict__ sig,
                                               uint16_t* __restrict__ xb,
                                               float* __restrict__ gate_out,
                                               int* __restrict__ counts,
                                               int* __restrict__ perm) {
    __shared__ float sl[NTILES * DMODEL];
    for (int i = threadIdx.x; i < NTILES * DMODEL; i += 256) sl[i] = sig[i];
    __syncthreads();
    int wave = threadIdx.x >> 6, lane = threadIdx.x & 63;
    int tok = blockIdx.x * 4 + wave;
    const float* xr = x + (size_t)tok * DMODEL;
    float sc[NTILES] = {0.f, 0.f, 0.f, 0.f};
    for (int q = 0; q < 4; ++q) {
        int c = q * 256 + lane * 4;
        float4 xv = *(const float4*)(xr + c);
        #pragma unroll
        for (int t = 0; t < NTILES; ++t) {
            const float* st = sl + t * DMODEL + c;
            sc[t] += xv.x * st[0] + xv.y * st[1] + xv.z * st[2] + xv.w * st[3];
        }
        ushort4 h;
        h.x = f2bf(xv.x); h.y = f2bf(xv.y); h.z = f2bf(xv.z); h.w = f2bf(xv.w);
        *(ushort4*)(xb + (size_t)tok * DMODEL + c) = h;
    }
    #pragma unroll
    for (int t = 0; t < NTILES; ++t)
        for (int off = 32; off; off >>= 1) sc[t] += __shfl_xor(sc[t], off);
    int w = 0; float best = sc[0];
    if (sc[1] > best) { best = sc[1]; w = 1; }
    if (sc[2] > best) { best = sc[2]; w = 2; }
    if (sc[3] > best) { best = sc[3]; w = 3; }
    if (lane < NTILES) gate_out[(size_t)tok * NTILES + lane] = (lane == w) ? 1.0f : 0.0f;
    if (lane == 0) {
        int pos = atomicAdd(&counts[w], 1);
        perm[w * NTOK + pos] = tok;
    }
}

// ---------------- fp32 -> bf16 convert (weights) ----------------
__global__ void k_conv(const float* __restrict__ src, uint16_t* __restrict__ dst, int n4) {
    int stride = gridDim.x * blockDim.x;
    for (int i = blockIdx.x * blockDim.x + threadIdx.x; i < n4; i += stride) {
        float4 v = *(const float4*)(src + (size_t)i * 4);
        ushort4 h;
        h.x = f2bf(v.x); h.y = f2bf(v.y); h.z = f2bf(v.z); h.w = f2bf(v.w);
        *(ushort4*)(dst + (size_t)i * 4) = h;
    }
}

// ---------------- grouped NT GEMM (m97 structure): C[128 x 128] per block ----------------
// A rows gathered via perm (tokens), B = expert weight rows, K contiguous in both.
// UP: A=xb (K=1024), B=wupb, out=hidden bf16 with ReLU.  DOWN: A=hidden (K=4096), B=wdownb, out=f32.
template <int K, bool UP>
__global__ void __launch_bounds__(256) k_ffn(const uint16_t* __restrict__ A,
                                             const uint16_t* __restrict__ Bw,
                                             const int* __restrict__ counts,
                                             const int* __restrict__ perm,
                                             uint16_t* __restrict__ hid_out,
                                             float* __restrict__ out) {
    constexpr int NOUT = UP ? DFF : DMODEL;
    int e = blockIdx.z;
    int cnt = counts[e];
    int base = blockIdx.y * 128;
    if (base >= cnt) return;
    int bn0 = blockIdx.x * 128;
    int lane = threadIdx.x & 63, w = threadIdx.x >> 6;
    int wr = w >> 1, wc = w & 1;
    const int* permE = perm + e * NTOK;

    __shared__ uint16_t lA[128 * 32];
    __shared__ uint16_t lB[128 * 32];

    // staging sources: wave w stages LDS chunks (2w) and (2w+1) of both tiles
    const uint16_t* gA[2];
    const uint16_t* gB[2];
    #pragma unroll
    for (int j = 0; j < 2; ++j) {
        int r  = (2 * w + j) * 16 + (lane >> 2);
        int rr = base + r;
        int tokr = permE[(rr < cnt) ? rr : base];
        gA[j] = A + (size_t)tokr * K + (lane & 3) * 8;
        gB[j] = Bw + ((size_t)e * NOUT + bn0 + r) * K + (lane & 3) * 8;
    }
    uint16_t* lAc0 = lA + (2 * w + 0) * 512;
    uint16_t* lAc1 = lA + (2 * w + 1) * 512;
    uint16_t* lBc0 = lB + (2 * w + 0) * 512;
    uint16_t* lBc1 = lB + (2 * w + 1) * 512;

    f32x4 acc[4][4];
    #pragma unroll
    for (int m = 0; m < 4; ++m)
        #pragma unroll
        for (int n = 0; n < 4; ++n) acc[m][n] = (f32x4){0.f, 0.f, 0.f, 0.f};

    const uint16_t* pa = lA + ((wr * 64 + (lane & 15)) * 32 + (lane >> 4) * 8);
    const uint16_t* pb = lB + ((wc * 64 + (lane & 15)) * 32 + (lane >> 4) * 8);

    #pragma unroll 1
    for (int k0 = 0; k0 < K; k0 += 32) {
        GLOAD_LDS16(gA[0] + k0, lAc0);
        GLOAD_LDS16(gA[1] + k0, lAc1);
        GLOAD_LDS16(gB[0] + k0, lBc0);
        GLOAD_LDS16(gB[1] + k0, lBc1);
        __syncthreads();   // drains vmcnt before barrier (m97 pattern)
        bf16x8 aF[4], bF[4];
        #pragma unroll
        for (int m = 0; m < 4; ++m) aF[m] = *(const bf16x8*)(pa + m * 16 * 32);
        #pragma unroll
        for (int n = 0; n < 4; ++n) bF[n] = *(const bf16x8*)(pb + n * 16 * 32);
        #pragma unroll
        for (int m = 0; m < 4; ++m)
            #pragma unroll
            for (int n = 0; n < 4; ++n)
                acc[m][n] = __builtin_amdgcn_mfma_f32_16x16x32_bf16(aF[m], bF[n], acc[m][n], 0, 0, 0);
        __syncthreads();
    }

    // epilogue: C[r][c], r = wr*64 + m*16 + (lane>>4)*4 + i, c = wc*64 + n*16 + (lane&15)
    #pragma unroll
    for (int m = 0; m < 4; ++m) {
        #pragma unroll
        for (int i = 0; i < 4; ++i) {
            int r  = wr * 64 + m * 16 + (lane >> 4) * 4 + i;
            int rr = base + r;
            if (rr < cnt) {
                int tok = permE[rr];
                if constexpr (UP) {
                    uint16_t* hr = hid_out + (size_t)tok * DFF + bn0 + wc * 64;
                    #pragma unroll
                    for (int n = 0; n < 4; ++n) {
                        float v = acc[m][n][i];
                        v = v > 0.f ? v : 0.f;   // ReLU
                        hr[n * 16 + (lane & 15)] = f2bf(v);
                    }
                } else {
                    float* orow = out + (size_t)tok * DMODEL + bn0 + wc * 64;
                    #pragma unroll
                    for (int n = 0; n < 4; ++n)
                        orow[n * 16 + (lane & 15)] = acc[m][n][i];
                }
            }
        }
    }
}

extern "C" void kernel_launch(void* const* d_in, const int* in_sizes, int n_in,
                              void* d_out, int out_size, void* d_ws, size_t ws_size,
                              hipStream_t stream) {
    const float* x     = (const float*)d_in[0];
    const float* Wup   = (const float*)d_in[1];
    const float* Wdown = (const float*)d_in[2];
    float* out  = (float*)d_out;
    float* gate = out + (size_t)NTOK * DMODEL;

    char* ws = (char*)d_ws;
    size_t off = 0;
    auto alloc = [&](size_t bytes) -> void* {
        void* p = ws + off;
        off += (bytes + 255) & ~(size_t)255;
        return p;
    };
    int*      counts  = (int*)alloc(NTILES * sizeof(int));
    float*    sig     = (float*)alloc((size_t)NTILES * DMODEL * sizeof(float));
    double*   partial = (double*)alloc((size_t)NTILES * DMODEL * 8 * sizeof(double));
    int*      perm    = (int*)alloc((size_t)NTILES * NTOK * sizeof(int));
    uint16_t* xb      = (uint16_t*)alloc((size_t)NTOK * DMODEL * 2);
    uint16_t* wupb    = (uint16_t*)alloc((size_t)NTILES * DFF * DMODEL * 2);
    uint16_t* wdownb  = (uint16_t*)alloc((size_t)NTILES * DMODEL * DFF * 2);
    uint16_t* hidden  = (uint16_t*)alloc((size_t)NTOK * DFF * 2);
    if (off > ws_size) return;   // ws too small: fail visibly, restructure next round

    hipLaunchKernelGGL(k_init, dim3(1), dim3(64), 0, stream, counts);
    hipLaunchKernelGGL(k_sig_partial, dim3(8, 16, 4), dim3(256), 0, stream, Wup, partial);
    hipLaunchKernelGGL(k_sig_final, dim3(16), dim3(256), 0, stream, partial, sig);
    hipLaunchKernelGGL(k_route, dim3(NTOK / 4), dim3(256), 0, stream,
                       x, sig, xb, gate, counts, perm);
    hipLaunchKernelGGL(k_conv, dim3(2048), dim3(256), 0, stream,
                       Wup, wupb, NTILES * DFF * DMODEL / 4);
    hipLaunchKernelGGL(k_conv, dim3(2048), dim3(256), 0, stream,
                       Wdown, wdownb, NTILES * DMODEL * DFF / 4);
    hipLaunchKernelGGL((k_ffn<DMODEL, true>), dim3(DFF / 128, 128, 4), dim3(256), 0, stream,
                       xb, wupb, counts, perm, hidden, nullptr);
    hipLaunchKernelGGL((k_ffn<DFF, false>), dim3(DMODEL / 128, 128, 4), dim3(256), 0, stream,
                       hidden, wdownb, counts, perm, nullptr, out);
}

// Round 2
// 631.962 us; speedup vs baseline: 1.1926x; 1.1926x over previous
//
#include <hip/hip_runtime.h>
#include <hip/hip_bf16.h>
#include <stdint.h>

#define NTILES 4
#define DMODEL 1024
#define DFF    4096
#define NTOK   16384

typedef __bf16 bf16x8 __attribute__((ext_vector_type(8)));
typedef float  f32x4  __attribute__((ext_vector_type(4)));

__device__ __forceinline__ uint16_t f2bf(float f) {
    union { float f; uint32_t u; } v; v.f = f;
    uint32_t u = v.u;
    uint32_t r = (u + 0x7fffu + ((u >> 16) & 1u)) >> 16;
    return (uint16_t)r;
}

#define STG(gptr, ldsoff) __builtin_amdgcn_global_load_lds( \
    (__attribute__((address_space(1))) void*)(gptr), \
    (__attribute__((address_space(3))) void*)(smem + (ldsoff)), 16, 0, 0)

// ---------------- init: zero expert counts ----------------
__global__ void k_init(int* counts) {
    if (threadIdx.x < NTILES) counts[threadIdx.x] = 0;
}

// ---------------- fused Wup fp32->bf16 convert + signature partial sums ----------------
// grid (64 fb, 4 e), 256 threads; block handles 64 f-rows x 1024 cols.
__global__ void k_convup(const float* __restrict__ Wup, uint16_t* __restrict__ wupb,
                         double* __restrict__ partial) {
    int e = blockIdx.y, fb = blockIdx.x, tid = threadIdx.x;
    const float* src = Wup + (size_t)e * DFF * DMODEL + (size_t)fb * 64 * DMODEL + tid * 4;
    uint16_t*    dst = wupb + (size_t)e * DFF * DMODEL + (size_t)fb * 64 * DMODEL + tid * 4;
    double s0 = 0, s1 = 0, s2 = 0, s3 = 0;
    for (int i = 0; i < 64; ++i) {
        float4 v = *(const float4*)(src + (size_t)i * DMODEL);
        ushort4 h;
        h.x = f2bf(v.x); h.y = f2bf(v.y); h.z = f2bf(v.z); h.w = f2bf(v.w);
        *(ushort4*)(dst + (size_t)i * DMODEL) = h;
        s0 += v.x; s1 += v.y; s2 += v.z; s3 += v.w;
    }
    int c = tid * 4;
    double* p = partial + ((size_t)e * DMODEL + c) * 64 + fb;
    p[0 * 64] = s0; p[1 * 64] = s1; p[2 * 64] = s2; p[3 * 64] = s3;
}

__global__ void k_sig_final(const double* __restrict__ partial, float* __restrict__ sig) {
    int idx = blockIdx.x * 256 + threadIdx.x;   // 0..4095
    double s = 0.0;
    for (int fb = 0; fb < 64; ++fb) s += partial[(size_t)idx * 64 + fb];
    sig[idx] = (s > 0.0) ? 1.0f : ((s < 0.0) ? -1.0f : 0.0f);
}

// ---------------- routing: scores, argmax, gate, xb (bf16 copy), buckets ----------------
__global__ void __launch_bounds__(256) k_route(const float* __restrict__ x,
                                               const float* __restrict__ sig,
                                               uint16_t* __restrict__ xb,
                                               float* __restrict__ gate_out,
                                               int* __restrict__ counts,
                                               int* __restrict__ perm) {
    __shared__ float sl[NTILES * DMODEL];
    for (int i = threadIdx.x; i < NTILES * DMODEL; i += 256) sl[i] = sig[i];
    __syncthreads();
    int wave = threadIdx.x >> 6, lane = threadIdx.x & 63;
    int tok = blockIdx.x * 4 + wave;
    const float* xr = x + (size_t)tok * DMODEL;
    float sc[NTILES] = {0.f, 0.f, 0.f, 0.f};
    for (int q = 0; q < 4; ++q) {
        int c = q * 256 + lane * 4;
        float4 xv = *(const float4*)(xr + c);
        #pragma unroll
        for (int t = 0; t < NTILES; ++t) {
            const float* st = sl + t * DMODEL + c;
            sc[t] += xv.x * st[0] + xv.y * st[1] + xv.z * st[2] + xv.w * st[3];
        }
        ushort4 h;
        h.x = f2bf(xv.x); h.y = f2bf(xv.y); h.z = f2bf(xv.z); h.w = f2bf(xv.w);
        *(ushort4*)(xb + (size_t)tok * DMODEL + c) = h;
    }
    #pragma unroll
    for (int t = 0; t < NTILES; ++t)
        for (int off = 32; off; off >>= 1) sc[t] += __shfl_xor(sc[t], off);
    int w = 0; float best = sc[0];
    if (sc[1] > best) { best = sc[1]; w = 1; }
    if (sc[2] > best) { best = sc[2]; w = 2; }
    if (sc[3] > best) { best = sc[3]; w = 3; }
    if (lane < NTILES) gate_out[(size_t)tok * NTILES + lane] = (lane == w) ? 1.0f : 0.0f;
    if (lane == 0) {
        int pos = atomicAdd(&counts[w], 1);
        perm[w * NTOK + pos] = tok;
    }
}

// ---------------- fp32 -> bf16 convert (Wdown) ----------------
__global__ void k_conv(const float* __restrict__ src, uint16_t* __restrict__ dst, int n4) {
    int stride = gridDim.x * blockDim.x;
    for (int i = blockIdx.x * blockDim.x + threadIdx.x; i < n4; i += stride) {
        float4 v = *(const float4*)(src + (size_t)i * 4);
        ushort4 h;
        h.x = f2bf(v.x); h.y = f2bf(v.y); h.z = f2bf(v.z); h.w = f2bf(v.w);
        *(ushort4*)(dst + (size_t)i * 4) = h;
    }
}

// ---------------- grouped NT GEMM, deep-pipelined ----------------
// BM=128 (tokens, gathered via perm), BN=256 (weight rows), BK=64.
// 512 threads = 8 waves as 2(M) x 4(N); per-wave output 64x64 (4x4 fragments).
// LDS: 3-slot ring, slot = A[128][64] (16KB) + B[256][64] (32KB) = 48KB; 144KB total.
// Stage 2 K-tiles ahead: slot being written holds tile t-1 (fully read before
// group t started) -> race-free by construction. Boundary wait = vmcnt(6).
// LDS swizzle: phys = logical ^ ((row&7)<<4)  (128B rows, 8x16B slots).
#define SLOT 49152

template <int K, bool UP>
__global__ void __launch_bounds__(512, 2)
k_ffn2(const uint16_t* __restrict__ A, const uint16_t* __restrict__ Bw,
       const int* __restrict__ counts, const int* __restrict__ perm,
       uint16_t* __restrict__ hid_out, float* __restrict__ out) {
    constexpr int NOUT = UP ? DFF : DMODEL;
    constexpr int NT = K / 64;
    extern __shared__ char smem[];

    const int e = blockIdx.z;
    const int cnt = counts[e];
    const int base = blockIdx.y * 128;
    if (base >= cnt) return;
    const int bn0 = blockIdx.x * 256;
    const int tid = threadIdx.x;
    const int lane = tid & 63, wid = tid >> 6;
    const int wr = wid >> 2, wc = wid & 3;
    const int* permE = perm + e * NTOK;

    // staging source pointers (inverse-swizzled global columns, rule #21)
    const uint16_t* gA[2];
    #pragma unroll
    for (int j = 0; j < 2; ++j) {
        int r  = wid * 16 + j * 8 + (lane >> 3);
        int rr = base + r;
        int tok = permE[(rr < cnt) ? rr : base];
        int c8 = (lane & 7) ^ (r & 7);
        gA[j] = A + (size_t)tok * K + c8 * 8;
    }
    const uint16_t* gB[4];
    #pragma unroll
    for (int j = 0; j < 4; ++j) {
        int r  = wid * 32 + j * 8 + (lane >> 3);
        int c8 = (lane & 7) ^ (r & 7);
        gB[j] = Bw + ((size_t)e * NOUT + bn0 + r) * K + c8 * 8;
    }
    const int ldsA = wid * 2048;            // A staging dest base (within slot)
    const int ldsB = 16384 + wid * 4096;    // B staging dest base

    // swizzled read offsets (XOR term is per-thread constant)
    const int Aoff = (wr * 64 + (lane & 15)) * 128;
    const int Boff = 16384 + (wc * 64 + (lane & 15)) * 128;
    const int inrow0 = (((lane >> 4) * 16)      ) ^ ((lane & 7) << 4);
    const int inrow1 = (64 + ((lane >> 4) * 16)) ^ ((lane & 7) << 4);

    f32x4 acc[4][4];
    #pragma unroll
    for (int m = 0; m < 4; ++m)
        #pragma unroll
        for (int n = 0; n < 4; ++n) acc[m][n] = (f32x4){0.f, 0.f, 0.f, 0.f};

    // prologue: stage tiles 0 -> slot0, 1 -> slot1 (6 instr each)
    #define STAGE_TILE(S, T) do { \
        STG(gA[0] + (T) * 64, (S) * SLOT + ldsA); \
        STG(gA[1] + (T) * 64, (S) * SLOT + ldsA + 1024); \
        STG(gB[0] + (T) * 64, (S) * SLOT + ldsB); \
        STG(gB[1] + (T) * 64, (S) * SLOT + ldsB + 1024); \
        STG(gB[2] + (T) * 64, (S) * SLOT + ldsB + 2048); \
        STG(gB[3] + (T) * 64, (S) * SLOT + ldsB + 3072); \
    } while (0)
    STAGE_TILE(0, 0);
    STAGE_TILE(1, 1);
    asm volatile("s_waitcnt vmcnt(6)" ::: "memory");
    __builtin_amdgcn_sched_barrier(0);
    __builtin_amdgcn_s_barrier();

    int cs = 0;
    #pragma unroll 1
    for (int t = 0; t < NT; ++t) {
        const char* sp = smem + cs * SLOT;
        const bool pre = (t + 2) < NT;
        const int ss = (cs == 0) ? 2 : cs - 1;   // (t+2)%3

        // ---- phase 0 (kk = 0) ----
        {
            bf16x8 aF[4], bF[4];
            #pragma unroll
            for (int m = 0; m < 4; ++m) aF[m] = *(const bf16x8*)(sp + Aoff + m * 2048 + inrow0);
            #pragma unroll
            for (int n = 0; n < 4; ++n) bF[n] = *(const bf16x8*)(sp + Boff + n * 2048 + inrow0);
            if (pre) {
                STG(gA[0] + (t + 2) * 64, ss * SLOT + ldsA);
                STG(gA[1] + (t + 2) * 64, ss * SLOT + ldsA + 1024);
                STG(gB[0] + (t + 2) * 64, ss * SLOT + ldsB);
            }
            __builtin_amdgcn_s_barrier();
            asm volatile("s_waitcnt lgkmcnt(0)" ::: "memory");
            __builtin_amdgcn_sched_barrier(0);
            __builtin_amdgcn_s_setprio(1);
            #pragma unroll
            for (int m = 0; m < 4; ++m)
                #pragma unroll
                for (int n = 0; n < 4; ++n)
                    acc[m][n] = __builtin_amdgcn_mfma_f32_16x16x32_bf16(aF[m], bF[n], acc[m][n], 0, 0, 0);
            __builtin_amdgcn_s_setprio(0);
            __builtin_amdgcn_s_barrier();
        }
        // ---- phase 1 (kk = 1) ----
        {
            bf16x8 aF[4], bF[4];
            #pragma unroll
            for (int m = 0; m < 4; ++m) aF[m] = *(const bf16x8*)(sp + Aoff + m * 2048 + inrow1);
            #pragma unroll
            for (int n = 0; n < 4; ++n) bF[n] = *(const bf16x8*)(sp + Boff + n * 2048 + inrow1);
            if (pre) {
                STG(gB[1] + (t + 2) * 64, ss * SLOT + ldsB + 1024);
                STG(gB[2] + (t + 2) * 64, ss * SLOT + ldsB + 2048);
                STG(gB[3] + (t + 2) * 64, ss * SLOT + ldsB + 3072);
            }
            __builtin_amdgcn_s_barrier();
            asm volatile("s_waitcnt lgkmcnt(0)" ::: "memory");
            __builtin_amdgcn_sched_barrier(0);
            __builtin_amdgcn_s_setprio(1);
            #pragma unroll
            for (int m = 0; m < 4; ++m)
                #pragma unroll
                for (int n = 0; n < 4; ++n)
                    acc[m][n] = __builtin_amdgcn_mfma_f32_16x16x32_bf16(aF[m], bF[n], acc[m][n], 0, 0, 0);
            __builtin_amdgcn_s_setprio(0);
            if (pre) { asm volatile("s_waitcnt vmcnt(6)" ::: "memory"); }
            else     { asm volatile("s_waitcnt vmcnt(0)" ::: "memory"); }
            __builtin_amdgcn_sched_barrier(0);
            __builtin_amdgcn_s_barrier();
        }
        cs = (cs == 2) ? 0 : cs + 1;
    }

    // epilogue
    #pragma unroll
    for (int m = 0; m < 4; ++m) {
        #pragma unroll
        for (int i = 0; i < 4; ++i) {
            int r  = wr * 64 + m * 16 + (lane >> 4) * 4 + i;
            int rr = base + r;
            if (rr < cnt) {
                int tok = permE[rr];
                if constexpr (UP) {
                    uint16_t* hr = hid_out + (size_t)tok * DFF + bn0 + wc * 64;
                    #pragma unroll
                    for (int n = 0; n < 4; ++n) {
                        float v = acc[m][n][i];
                        v = v > 0.f ? v : 0.f;
                        hr[n * 16 + (lane & 15)] = f2bf(v);
                    }
                } else {
                    float* orow = out + (size_t)tok * DMODEL + bn0 + wc * 64;
                    #pragma unroll
                    for (int n = 0; n < 4; ++n)
                        orow[n * 16 + (lane & 15)] = acc[m][n][i];
                }
            }
        }
    }
}

extern "C" void kernel_launch(void* const* d_in, const int* in_sizes, int n_in,
                              void* d_out, int out_size, void* d_ws, size_t ws_size,
                              hipStream_t stream) {
    const float* x     = (const float*)d_in[0];
    const float* Wup   = (const float*)d_in[1];
    const float* Wdown = (const float*)d_in[2];
    float* out  = (float*)d_out;
    float* gate = out + (size_t)NTOK * DMODEL;

    char* ws = (char*)d_ws;
    size_t off = 0;
    auto alloc = [&](size_t bytes) -> void* {
        void* p = ws + off;
        off += (bytes + 255) & ~(size_t)255;
        return p;
    };
    int*      counts  = (int*)alloc(NTILES * sizeof(int));
    float*    sig     = (float*)alloc((size_t)NTILES * DMODEL * sizeof(float));
    double*   partial = (double*)alloc((size_t)NTILES * DMODEL * 64 * sizeof(double));
    int*      perm    = (int*)alloc((size_t)NTILES * NTOK * sizeof(int));
    uint16_t* xb      = (uint16_t*)alloc((size_t)NTOK * DMODEL * 2);
    uint16_t* wupb    = (uint16_t*)alloc((size_t)NTILES * DFF * DMODEL * 2);
    uint16_t* wdownb  = (uint16_t*)alloc((size_t)NTILES * DMODEL * DFF * 2);
    uint16_t* hidden  = (uint16_t*)alloc((size_t)NTOK * DFF * 2);
    if (off > ws_size) return;

    hipFuncSetAttribute((const void*)&k_ffn2<DMODEL, true>,
                        hipFuncAttributeMaxDynamicSharedMemorySize, 3 * SLOT);
    hipFuncSetAttribute((const void*)&k_ffn2<DFF, false>,
                        hipFuncAttributeMaxDynamicSharedMemorySize, 3 * SLOT);

    hipLaunchKernelGGL(k_init, dim3(1), dim3(64), 0, stream, counts);
    hipLaunchKernelGGL(k_convup, dim3(64, 4), dim3(256), 0, stream, Wup, wupb, partial);
    hipLaunchKernelGGL(k_sig_final, dim3(16), dim3(256), 0, stream, partial, sig);
    hipLaunchKernelGGL(k_route, dim3(NTOK / 4), dim3(256), 0, stream,
                       x, sig, xb, gate, counts, perm);
    hipLaunchKernelGGL(k_conv, dim3(2048), dim3(256), 0, stream,
                       Wdown, wdownb, NTILES * DMODEL * DFF / 4);
    hipLaunchKernelGGL((k_ffn2<DMODEL, true>), dim3(DFF / 256, NTOK / 128, NTILES),
                       dim3(512), 3 * SLOT, stream, xb, wupb, counts, perm, hidden, nullptr);
    hipLaunchKernelGGL((k_ffn2<DFF, false>), dim3(DMODEL / 256, NTOK / 128, NTILES),
                       dim3(512), 3 * SLOT, stream, hidden, wdownb, counts, perm, nullptr, out);
}